// Round 3
// baseline (555.468 us; speedup 1.0000x reference)
//
#include <hip/hip_runtime.h>

#define BSZ 512
#define NNODE 30
#define KNBR 15
#define HID 128
#define MTOT (BSZ*NNODE)   // 15360

__device__ __forceinline__ float frelu(float x){ return x > 0.f ? x : 0.f; }

// node coordinates per Q layout
__device__ __forceinline__ void node_coords(const float* __restrict__ st,
                                            const float* __restrict__ ac,
                                            int b, int n, int qsel, float c[4]) {
    if (qsel == 0) {
        // interleaved per-box [sx, sy, ax, ay]
        c[0] = st[b*60 + 2*n];     c[1] = st[b*60 + 2*n + 1];
        c[2] = ac[b*60 + 2*n];     c[3] = ac[b*60 + 2*n + 1];
    } else {
        // cat([state, action], dim=1).view(-1,4): n<15 all-state, n>=15 all-action
        int base = 4*n;
        if (base < 60) {
            c[0]=st[b*60+base]; c[1]=st[b*60+base+1]; c[2]=st[b*60+base+2]; c[3]=st[b*60+base+3];
        } else {
            int a = base - 60;
            c[0]=ac[b*60+a]; c[1]=ac[b*60+a+1]; c[2]=ac[b*60+a+2]; c[3]=ac[b*60+a+3];
        }
    }
}

// Wcomb[256][128]: rows 0..127 = Wa_L - Wa_R (v-part), rows 128..255 = Wa_R (v-part)
__global__ void k_wcomb(const float* __restrict__ Wa, float* __restrict__ Wcomb) {
    int t = blockIdx.x*256 + threadIdx.x;
    if (t >= 256*128) return;
    int o = t >> 7, h = t & 127;
    float v;
    if (o < 128) v = Wa[o*388 + h] - Wa[o*388 + 194 + h];
    else         v = Wa[(o-128)*388 + 194 + h];
    Wcomb[t] = v;
}

// clsA[c][o] = (Wa_L-Wa_R)[:,128:192] @ relu(emb[c]) + b_m1a ;  clsB[c][o] = Wa_R[:,128:192] @ relu(emb[c])
__global__ void k_cls(const float* __restrict__ Wa, const float* __restrict__ ba,
                      const float* __restrict__ emb,
                      float* __restrict__ clsA, float* __restrict__ clsB) {
    int o = threadIdx.x;   // 128 threads
    for (int c = 0; c < 3; ++c) {
        float sA = ba[o], sB = 0.f;
        for (int e = 0; e < 64; ++e) {
            float r  = frelu(emb[c*64 + e]);
            float wl = Wa[o*388 + 128 + e];
            float wr = Wa[o*388 + 194 + 128 + e];
            sA += (wl - wr) * r;
            sB += wr * r;
        }
        clsA[c*128 + o] = sA;
        clsB[c*128 + o] = sB;
    }
}

// V[m][h] = relu(W_init @ node_m + b_init)
__global__ void k_nodesV(const float* __restrict__ st, const float* __restrict__ ac,
                         const float* __restrict__ Wi, const float* __restrict__ bi,
                         int qsel, float* __restrict__ V) {
    int gid = blockIdx.x*256 + threadIdx.x;
    if (gid >= MTOT*128) return;
    int m = gid >> 7, h = gid & 127;
    int b = m / 30, n = m % 30;
    float c[4]; node_coords(st, ac, b, n, qsel, c);
    float acc = bi[h] + Wi[h*4+0]*c[0] + Wi[h*4+1]*c[1] + Wi[h*4+2]*c[2] + Wi[h*4+3]*c[3];
    V[m*128 + h] = frelu(acc);
}

// exact kNN (matches top_k(-d,k): strictly-smallest-first, ties -> lower index)
__global__ void k_knn(const float* __restrict__ st, const float* __restrict__ ac,
                      int qsel, int* __restrict__ idx) {
    int gid = blockIdx.x*128 + threadIdx.x;
    if (gid >= MTOT) return;
    int b = gid / 30, i = gid % 30;
    float ci[4]; node_coords(st, ac, b, i, qsel, ci);
    float d[30];
    #pragma unroll
    for (int j = 0; j < 30; ++j) {
        float cj[4]; node_coords(st, ac, b, j, qsel, cj);
        float d0 = ci[0]-cj[0], d1 = ci[1]-cj[1], d2 = ci[2]-cj[2], d3 = ci[3]-cj[3];
        d[j] = d0*d0 + d1*d1 + d2*d2 + d3*d3;
    }
    unsigned mask = 1u << i;   // exclude self
    for (int k = 0; k < KNBR; ++k) {
        float best = 3.4e38f; int bj = 0;
        #pragma unroll
        for (int j = 0; j < 30; ++j) {
            bool ok = !((mask >> j) & 1u) && (d[j] < best);
            if (ok) { best = d[j]; bj = j; }
        }
        mask |= 1u << bj;
        idx[gid*KNBR + k] = b*30 + bj;   // store global node index
    }
}

// [A;B] = V @ Wcomb^T, plus per-category bias. 64x64 tile, 4x4 per thread.
__global__ void __launch_bounds__(256) k_AB(const float* __restrict__ V, const float* __restrict__ Wcomb,
                                            const float* __restrict__ clsA, const float* __restrict__ clsB,
                                            float* __restrict__ A, float* __restrict__ B) {
    __shared__ float Vs[64][68];
    __shared__ float Ws[64][68];
    int tid = threadIdx.x;
    int tx = tid & 15, ty = tid >> 4;
    int m0 = blockIdx.x * 64, n0 = blockIdx.y * 64;
    float acc[4][4] = {};
    for (int kc = 0; kc < 2; ++kc) {
        for (int f = tid; f < 64*16; f += 256) {
            int r = f >> 4, k4 = f & 15;
            *(float4*)&Vs[r][k4*4] = *(const float4*)&V[(m0+r)*128 + kc*64 + k4*4];
        }
        for (int f = tid; f < 64*16; f += 256) {
            int r = f >> 4, k4 = f & 15;
            *(float4*)&Ws[r][k4*4] = *(const float4*)&Wcomb[(n0+r)*128 + kc*64 + k4*4];
        }
        __syncthreads();
        #pragma unroll
        for (int k4 = 0; k4 < 16; ++k4) {
            float4 a[4], w[4];
            #pragma unroll
            for (int i = 0; i < 4; ++i) a[i] = *(float4*)&Vs[ty*4+i][k4*4];
            #pragma unroll
            for (int j = 0; j < 4; ++j) w[j] = *(float4*)&Ws[tx*4+j][k4*4];
            #pragma unroll
            for (int i = 0; i < 4; ++i)
                #pragma unroll
                for (int j = 0; j < 4; ++j)
                    acc[i][j] += a[i].x*w[j].x + a[i].y*w[j].y + a[i].z*w[j].z + a[i].w*w[j].w;
        }
        __syncthreads();
    }
    bool isA = (n0 < 128);
    const float* cls = isA ? clsA : clsB;
    float* dst = isA ? A : B;
    int ob = isA ? n0 : (n0 - 128);
    #pragma unroll
    for (int i = 0; i < 4; ++i) {
        int m = m0 + ty*4 + i;
        int cat = (m % 30) / 10;
        int o = ob + tx*4;
        float4 bias = *(const float4*)&cls[cat*128 + o];
        float4 r = make_float4(acc[i][0]+bias.x, acc[i][1]+bias.y, acc[i][2]+bias.z, acc[i][3]+bias.w);
        *(float4*)&dst[m*128 + o] = r;
    }
}

// E[m][o] = relu( max_j (Wb @ relu(A_m + B_j))[o] + bb[o] ). 4 nodes/block, 128 threads.
__global__ void __launch_bounds__(128) k_edge(const float* __restrict__ A, const float* __restrict__ B,
                                              const int* __restrict__ idx, const float* __restrict__ Wb,
                                              const float* __restrict__ bb, float* __restrict__ E) {
    __shared__ float hbuf[4][15*132];   // per node: [j][h], row stride 132 (528B, 16B-aligned)
    int tid = threadIdx.x;
    int g = tid >> 5, l = tid & 31;
    int m = blockIdx.x*4 + g;

    // phase 1: h-edge values into LDS
    float4 a4 = *(const float4*)&A[m*128 + l*4];
    for (int j = 0; j < 15; ++j) {
        int nb = idx[m*15 + j];
        float4 b4 = *(const float4*)&B[nb*128 + l*4];
        float4 h4 = make_float4(frelu(a4.x+b4.x), frelu(a4.y+b4.y), frelu(a4.z+b4.z), frelu(a4.w+b4.w));
        *(float4*)&hbuf[g][j*132 + l*4] = h4;
    }
    __syncthreads();

    // phase 2: thread owns o = c*32+l (c=0..3), all 15 j
    float acc[15][4] = {};
    const float4* Wb4 = (const float4*)Wb;
    for (int h4 = 0; h4 < 32; ++h4) {
        float4 w[4];
        #pragma unroll
        for (int c = 0; c < 4; ++c) w[c] = Wb4[(c*32+l)*32 + h4];
        #pragma unroll
        for (int j = 0; j < 15; ++j) {
            float4 hv = *(float4*)&hbuf[g][j*132 + h4*4];
            #pragma unroll
            for (int c = 0; c < 4; ++c)
                acc[j][c] += hv.x*w[c].x + hv.y*w[c].y + hv.z*w[c].z + hv.w*w[c].w;
        }
    }
    #pragma unroll
    for (int c = 0; c < 4; ++c) {
        float mx = acc[0][c];
        #pragma unroll
        for (int j = 1; j < 15; ++j) mx = fmaxf(mx, acc[j][c]);
        int o = c*32 + l;
        E[m*128 + o] = frelu(mx + bb[o]);
    }
}

// q[m] = Wcb @ relu(Wca @ E_m + bca) + bcb. 8 nodes/block, 128 threads (thread = output channel).
__global__ void __launch_bounds__(128) k_head(const float* __restrict__ E, const float* __restrict__ Wca,
                                              const float* __restrict__ bca, const float* __restrict__ Wcb,
                                              const float* __restrict__ bcb,
                                              float* __restrict__ out, int qoff) {
    __shared__ float Es[8][128];
    __shared__ float red[128];
    int t = threadIdx.x;
    int m0 = blockIdx.x * 8;
    for (int f = t; f < 8*32; f += 128) {
        int nd = f >> 5, h4 = f & 31;
        *(float4*)&Es[nd][h4*4] = *(const float4*)&E[(m0+nd)*128 + h4*4];
    }
    __syncthreads();
    float acc[8] = {};
    const float4* W4 = (const float4*)Wca;
    for (int h4 = 0; h4 < 32; ++h4) {
        float4 w = W4[t*32 + h4];
        #pragma unroll
        for (int nd = 0; nd < 8; ++nd) {
            float4 e = *(float4*)&Es[nd][h4*4];
            acc[nd] += w.x*e.x + w.y*e.y + w.z*e.z + w.w*e.w;
        }
    }
    float wcb = Wcb[t], bca_t = bca[t], bcbv = bcb[0];
    for (int nd = 0; nd < 8; ++nd) {
        red[t] = frelu(acc[nd] + bca_t) * wcb;
        __syncthreads();
        if (t < 64) red[t] += red[t+64]; __syncthreads();
        if (t < 32) red[t] += red[t+32]; __syncthreads();
        if (t < 16) red[t] += red[t+16]; __syncthreads();
        if (t < 8)  red[t] += red[t+8];  __syncthreads();
        if (t < 4)  red[t] += red[t+4];  __syncthreads();
        if (t < 2)  red[t] += red[t+2];  __syncthreads();
        if (t == 0) out[qoff + m0 + nd] = red[0] + red[1] + bcbv;
        __syncthreads();
    }
}

extern "C" void kernel_launch(void* const* d_in, const int* in_sizes, int n_in,
                              void* d_out, int out_size, void* d_ws, size_t ws_size,
                              hipStream_t stream) {
    const float* state  = (const float*)d_in[0];
    const float* action = (const float*)d_in[1];
    const float* W_init1= (const float*)d_in[2];
    const float* b_init1= (const float*)d_in[3];
    const float* emb1   = (const float*)d_in[4];
    const float* W_m1a  = (const float*)d_in[5];
    const float* b_m1a  = (const float*)d_in[6];
    const float* W_m1b  = (const float*)d_in[7];
    const float* b_m1b  = (const float*)d_in[8];
    const float* W_c1a  = (const float*)d_in[9];
    const float* b_c1a  = (const float*)d_in[10];
    const float* W_c1b  = (const float*)d_in[11];
    const float* b_c1b  = (const float*)d_in[12];
    const float* W_init2= (const float*)d_in[13];
    const float* b_init2= (const float*)d_in[14];
    const float* emb2   = (const float*)d_in[15];
    const float* W_c2a  = (const float*)d_in[16];
    const float* b_c2a  = (const float*)d_in[17];
    const float* W_c2b  = (const float*)d_in[18];
    const float* b_c2b  = (const float*)d_in[19];

    float* ws    = (float*)d_ws;
    float* Wcomb = ws;                          // 32768 floats
    float* clsA  = ws + 32768;                  // 384
    float* clsB  = ws + 33152;                  // 384
    int*   idx   = (int*)(ws + 34816);          // 15360*15 ints = 230400
    float* V     = ws + 34816 + 230400;         // 15360*128 (doubles as E)
    float* A     = V + MTOT*128;                // 15360*128
    float* B     = A + MTOT*128;                // 15360*128
    float* out   = (float*)d_out;

    k_wcomb<<<128, 256, 0, stream>>>(W_m1a, Wcomb);

    for (int q = 0; q < 2; ++q) {
        const float* Wi  = q ? W_init2 : W_init1;
        const float* bi  = q ? b_init2 : b_init1;
        const float* emb = q ? emb2    : emb1;
        const float* Wca = q ? W_c2a   : W_c1a;
        const float* bca = q ? b_c2a   : b_c1a;
        const float* Wcb = q ? W_c2b   : W_c1b;
        const float* bcb = q ? b_c2b   : b_c1b;

        k_cls<<<1, 128, 0, stream>>>(W_m1a, b_m1a, emb, clsA, clsB);
        k_nodesV<<<(MTOT*128)/256, 256, 0, stream>>>(state, action, Wi, bi, q, V);
        k_knn<<<(MTOT+127)/128, 128, 0, stream>>>(state, action, q, idx);
        dim3 gAB(MTOT/64, 4);
        k_AB<<<gAB, 256, 0, stream>>>(V, Wcomb, clsA, clsB, A, B);
        k_edge<<<MTOT/4, 128, 0, stream>>>(A, B, idx, W_m1b, b_m1b, V);  // E aliases V
        k_head<<<MTOT/8, 128, 0, stream>>>(V, Wca, bca, Wcb, bcb, out, q*MTOT);
    }
}

// Round 5
// 391.655 us; speedup vs baseline: 1.4183x; 1.4183x over previous
//
#include <hip/hip_runtime.h>

#define BSZ 512
#define NNODE 30
#define KNBR 15
#define HID 128
#define MTOT (BSZ*NNODE)   // 15360

typedef __attribute__((ext_vector_type(8))) __bf16 bf16x8;
typedef __attribute__((ext_vector_type(4))) float f32x4;

__device__ __forceinline__ float frelu(float x){ return x > 0.f ? x : 0.f; }

// node coordinates per Q layout
__device__ __forceinline__ void node_coords(const float* __restrict__ st,
                                            const float* __restrict__ ac,
                                            int b, int n, int qsel, float c[4]) {
    if (qsel == 0) {
        c[0] = st[b*60 + 2*n];     c[1] = st[b*60 + 2*n + 1];
        c[2] = ac[b*60 + 2*n];     c[3] = ac[b*60 + 2*n + 1];
    } else {
        int base = 4*n;
        if (base < 60) {
            c[0]=st[b*60+base]; c[1]=st[b*60+base+1]; c[2]=st[b*60+base+2]; c[3]=st[b*60+base+3];
        } else {
            int a = base - 60;
            c[0]=ac[b*60+a]; c[1]=ac[b*60+a+1]; c[2]=ac[b*60+a+2]; c[3]=ac[b*60+a+3];
        }
    }
}

// Wcomb[256][128]: rows 0..127 = Wa_L - Wa_R (v-part), rows 128..255 = Wa_R (v-part)
__global__ void k_wcomb(const float* __restrict__ Wa, float* __restrict__ Wcomb) {
    int t = blockIdx.x*256 + threadIdx.x;
    if (t >= 256*128) return;
    int o = t >> 7, h = t & 127;
    float v;
    if (o < 128) v = Wa[o*388 + h] - Wa[o*388 + 194 + h];
    else         v = Wa[(o-128)*388 + 194 + h];
    Wcomb[t] = v;
}

// Wb (128x128 fp32, row-major [o][h]) -> bf16
__global__ void k_wb16(const float* __restrict__ W, __bf16* __restrict__ W16) {
    int t = blockIdx.x*256 + threadIdx.x;
    if (t < 128*128) W16[t] = (__bf16)W[t];
}

// clsA[c][o] = (Wa_L-Wa_R)[:,128:192] @ relu(emb[c]) + b_m1a ;  clsB[c][o] = Wa_R[:,128:192] @ relu(emb[c])
__global__ void k_cls(const float* __restrict__ Wa, const float* __restrict__ ba,
                      const float* __restrict__ emb,
                      float* __restrict__ clsA, float* __restrict__ clsB) {
    int o = threadIdx.x;   // 128 threads
    for (int c = 0; c < 3; ++c) {
        float sA = ba[o], sB = 0.f;
        for (int e = 0; e < 64; ++e) {
            float r  = frelu(emb[c*64 + e]);
            float wl = Wa[o*388 + 128 + e];
            float wr = Wa[o*388 + 194 + 128 + e];
            sA += (wl - wr) * r;
            sB += wr * r;
        }
        clsA[c*128 + o] = sA;
        clsB[c*128 + o] = sB;
    }
}

// V[m][h] = relu(W_init @ node_m + b_init)
__global__ void k_nodesV(const float* __restrict__ st, const float* __restrict__ ac,
                         const float* __restrict__ Wi, const float* __restrict__ bi,
                         int qsel, float* __restrict__ V) {
    int gid = blockIdx.x*256 + threadIdx.x;
    if (gid >= MTOT*128) return;
    int m = gid >> 7, h = gid & 127;
    int b = m / 30, n = m % 30;
    float c[4]; node_coords(st, ac, b, n, qsel, c);
    float acc = bi[h] + Wi[h*4+0]*c[0] + Wi[h*4+1]*c[1] + Wi[h*4+2]*c[2] + Wi[h*4+3]*c[3];
    V[m*128 + h] = frelu(acc);
}

// exact kNN (matches top_k(-d,k): strictly-smallest-first, ties -> lower index)
__global__ void k_knn(const float* __restrict__ st, const float* __restrict__ ac,
                      int qsel, int* __restrict__ idx) {
    int gid = blockIdx.x*128 + threadIdx.x;
    if (gid >= MTOT) return;
    int b = gid / 30, i = gid % 30;
    float ci[4]; node_coords(st, ac, b, i, qsel, ci);
    float d[30];
    #pragma unroll
    for (int j = 0; j < 30; ++j) {
        float cj[4]; node_coords(st, ac, b, j, qsel, cj);
        float d0 = ci[0]-cj[0], d1 = ci[1]-cj[1], d2 = ci[2]-cj[2], d3 = ci[3]-cj[3];
        d[j] = d0*d0 + d1*d1 + d2*d2 + d3*d3;
    }
    unsigned mask = 1u << i;   // exclude self
    for (int k = 0; k < KNBR; ++k) {
        float best = 3.4e38f; int bj = 0;
        #pragma unroll
        for (int j = 0; j < 30; ++j) {
            bool ok = !((mask >> j) & 1u) && (d[j] < best);
            if (ok) { best = d[j]; bj = j; }
        }
        mask |= 1u << bj;
        idx[gid*KNBR + k] = b*30 + bj;   // store global node index
    }
}

// [A;B] = V @ Wcomb^T, plus per-category bias. 64x64 tile, 4x4 per thread.
__global__ void __launch_bounds__(256) k_AB(const float* __restrict__ V, const float* __restrict__ Wcomb,
                                            const float* __restrict__ clsA, const float* __restrict__ clsB,
                                            float* __restrict__ A, float* __restrict__ B) {
    __shared__ float Vs[64][68];
    __shared__ float Ws[64][68];
    int tid = threadIdx.x;
    int tx = tid & 15, ty = tid >> 4;
    int m0 = blockIdx.x * 64, n0 = blockIdx.y * 64;
    float acc[4][4] = {};
    for (int kc = 0; kc < 2; ++kc) {
        for (int f = tid; f < 64*16; f += 256) {
            int r = f >> 4, k4 = f & 15;
            *(float4*)&Vs[r][k4*4] = *(const float4*)&V[(m0+r)*128 + kc*64 + k4*4];
        }
        for (int f = tid; f < 64*16; f += 256) {
            int r = f >> 4, k4 = f & 15;
            *(float4*)&Ws[r][k4*4] = *(const float4*)&Wcomb[(n0+r)*128 + kc*64 + k4*4];
        }
        __syncthreads();
        #pragma unroll
        for (int k4 = 0; k4 < 16; ++k4) {
            float4 a[4], w[4];
            #pragma unroll
            for (int i = 0; i < 4; ++i) a[i] = *(float4*)&Vs[ty*4+i][k4*4];
            #pragma unroll
            for (int j = 0; j < 4; ++j) w[j] = *(float4*)&Ws[tx*4+j][k4*4];
            #pragma unroll
            for (int i = 0; i < 4; ++i)
                #pragma unroll
                for (int j = 0; j < 4; ++j)
                    acc[i][j] += a[i].x*w[j].x + a[i].y*w[j].y + a[i].z*w[j].z + a[i].w*w[j].w;
        }
        __syncthreads();
    }
    bool isA = (n0 < 128);
    const float* cls = isA ? clsA : clsB;
    float* dst = isA ? A : B;
    int ob = isA ? n0 : (n0 - 128);
    #pragma unroll
    for (int i = 0; i < 4; ++i) {
        int m = m0 + ty*4 + i;
        int cat = (m % 30) / 10;
        int o = ob + tx*4;
        float4 bias = *(const float4*)&cls[cat*128 + o];
        float4 r = make_float4(acc[i][0]+bias.x, acc[i][1]+bias.y, acc[i][2]+bias.z, acc[i][3]+bias.w);
        *(float4*)&dst[m*128 + o] = r;
    }
}

// MFMA edge kernel: E[m][o] = relu( max_j (Wb @ relu(A_m + B_j))[o] + bb[o] )
// One node per wave-iteration: H (16 edges x 128 h) built in A-fragment layout,
// row 15 duplicates edge 0 (max unaffected). 8 oc-tiles x 4 kk MFMAs.
__global__ void __launch_bounds__(256) k_edge_mfma(
        const float* __restrict__ A, const float* __restrict__ B,
        const int* __restrict__ idx, const __bf16* __restrict__ Wb16,
        const float* __restrict__ bb, float* __restrict__ E) {
    int tid = threadIdx.x;
    int lane = tid & 63, wid = tid >> 6;
    int l15 = lane & 15, g = lane >> 4;

    // Wb fragments (B-operand): lane holds Wb[o=oc*16+l15][h=kk*32+g*8+e], e=0..7
    bf16x8 wbf[8][4];
    #pragma unroll
    for (int oc = 0; oc < 8; ++oc)
        #pragma unroll
        for (int kk = 0; kk < 4; ++kk)
            wbf[oc][kk] = *(const bf16x8*)(Wb16 + (oc*16 + l15)*128 + kk*32 + g*8);

    float bbv[8];
    #pragma unroll
    for (int oc = 0; oc < 8; ++oc) bbv[oc] = bb[oc*16 + l15];

    int jc = (l15 == 15) ? 0 : l15;   // edge row for this lane (15 -> dup of 0)

    for (int n = 0; n < 4; ++n) {
        int m = blockIdx.x*16 + wid*4 + n;
        int nb = idx[m*15 + jc];

        // H fragments (A-operand): lane holds H[j=l15][h=kk*32+g*8+e]
        bf16x8 hf[4];
        #pragma unroll
        for (int kk = 0; kk < 4; ++kk) {
            const float4* pa = (const float4*)(A + m*128 + kk*32 + g*8);
            const float4* pb = (const float4*)(B + (long)nb*128 + kk*32 + g*8);
            float4 a0 = pa[0], a1 = pa[1];
            float4 b0 = pb[0], b1 = pb[1];
            bf16x8 h;
            h[0]=(__bf16)frelu(a0.x+b0.x); h[1]=(__bf16)frelu(a0.y+b0.y);
            h[2]=(__bf16)frelu(a0.z+b0.z); h[3]=(__bf16)frelu(a0.w+b0.w);
            h[4]=(__bf16)frelu(a1.x+b1.x); h[5]=(__bf16)frelu(a1.y+b1.y);
            h[6]=(__bf16)frelu(a1.z+b1.z); h[7]=(__bf16)frelu(a1.w+b1.w);
            hf[kk] = h;
        }

        f32x4 acc[8];
        #pragma unroll
        for (int oc = 0; oc < 8; ++oc) acc[oc] = (f32x4){0.f,0.f,0.f,0.f};
        #pragma unroll
        for (int kk = 0; kk < 4; ++kk)
            #pragma unroll
            for (int oc = 0; oc < 8; ++oc)
                acc[oc] = __builtin_amdgcn_mfma_f32_16x16x32_bf16(hf[kk], wbf[oc][kk], acc[oc], 0, 0, 0);

        // max over 16 edge-rows: per-lane 4 regs, then across the 4 lane-groups
        #pragma unroll
        for (int oc = 0; oc < 8; ++oc) {
            float v = fmaxf(fmaxf(acc[oc][0], acc[oc][1]), fmaxf(acc[oc][2], acc[oc][3]));
            v = fmaxf(v, __shfl_xor(v, 16));
            v = fmaxf(v, __shfl_xor(v, 32));
            if (g == 0) E[m*128 + oc*16 + l15] = frelu(v + bbv[oc]);
        }
    }
}

// q[m] = Wcb @ relu(Wca @ E_m + bca) + bcb. 8 nodes/block, 128 threads (thread = output channel).
__global__ void __launch_bounds__(128) k_head(const float* __restrict__ E, const float* __restrict__ Wca,
                                              const float* __restrict__ bca, const float* __restrict__ Wcb,
                                              const float* __restrict__ bcb,
                                              float* __restrict__ out, int qoff) {
    __shared__ float Es[8][128];
    __shared__ float red[128];
    int t = threadIdx.x;
    int m0 = blockIdx.x * 8;
    for (int f = t; f < 8*32; f += 128) {
        int nd = f >> 5, h4 = f & 31;
        *(float4*)&Es[nd][h4*4] = *(const float4*)&E[(m0+nd)*128 + h4*4];
    }
    __syncthreads();
    float acc[8] = {};
    const float4* W4 = (const float4*)Wca;
    for (int h4 = 0; h4 < 32; ++h4) {
        float4 w = W4[t*32 + h4];
        #pragma unroll
        for (int nd = 0; nd < 8; ++nd) {
            float4 e = *(float4*)&Es[nd][h4*4];
            acc[nd] += w.x*e.x + w.y*e.y + w.z*e.z + w.w*e.w;
        }
    }
    float wcb = Wcb[t], bca_t = bca[t], bcbv = bcb[0];
    for (int nd = 0; nd < 8; ++nd) {
        red[t] = frelu(acc[nd] + bca_t) * wcb;
        __syncthreads();
        if (t < 64) red[t] += red[t+64]; __syncthreads();
        if (t < 32) red[t] += red[t+32]; __syncthreads();
        if (t < 16) red[t] += red[t+16]; __syncthreads();
        if (t < 8)  red[t] += red[t+8];  __syncthreads();
        if (t < 4)  red[t] += red[t+4];  __syncthreads();
        if (t < 2)  red[t] += red[t+2];  __syncthreads();
        if (t == 0) out[qoff + m0 + nd] = red[0] + red[1] + bcbv;
        __syncthreads();
    }
}

extern "C" void kernel_launch(void* const* d_in, const int* in_sizes, int n_in,
                              void* d_out, int out_size, void* d_ws, size_t ws_size,
                              hipStream_t stream) {
    const float* state  = (const float*)d_in[0];
    const float* action = (const float*)d_in[1];
    const float* W_init1= (const float*)d_in[2];
    const float* b_init1= (const float*)d_in[3];
    const float* emb1   = (const float*)d_in[4];
    const float* W_m1a  = (const float*)d_in[5];
    const float* b_m1a  = (const float*)d_in[6];
    const float* W_m1b  = (const float*)d_in[7];
    const float* b_m1b  = (const float*)d_in[8];
    const float* W_c1a  = (const float*)d_in[9];
    const float* b_c1a  = (const float*)d_in[10];
    const float* W_c1b  = (const float*)d_in[11];
    const float* b_c1b  = (const float*)d_in[12];
    const float* W_init2= (const float*)d_in[13];
    const float* b_init2= (const float*)d_in[14];
    const float* emb2   = (const float*)d_in[15];
    const float* W_c2a  = (const float*)d_in[16];
    const float* b_c2a  = (const float*)d_in[17];
    const float* W_c2b  = (const float*)d_in[18];
    const float* b_c2b  = (const float*)d_in[19];

    float* ws    = (float*)d_ws;
    float* Wcomb = ws;                          // 32768 floats
    float* clsA  = ws + 32768;                  // 384
    float* clsB  = ws + 33152;                  // 384
    int*   idx   = (int*)(ws + 34816);          // 15360*15 ints = 230400
    float* V     = ws + 34816 + 230400;         // 15360*128 (doubles as E)
    float* A     = V + MTOT*128;                // 15360*128
    float* B     = A + MTOT*128;                // 15360*128
    __bf16* Wb16 = (__bf16*)(B + MTOT*128);     // 16384 bf16 = 32KB
    float* out   = (float*)d_out;

    k_wcomb<<<128, 256, 0, stream>>>(W_m1a, Wcomb);
    k_wb16<<<64, 256, 0, stream>>>(W_m1b, Wb16);

    for (int q = 0; q < 2; ++q) {
        const float* Wi  = q ? W_init2 : W_init1;
        const float* bi  = q ? b_init2 : b_init1;
        const float* emb = q ? emb2    : emb1;
        const float* Wca = q ? W_c2a   : W_c1a;
        const float* bca = q ? b_c2a   : b_c1a;
        const float* Wcb = q ? W_c2b   : W_c1b;
        const float* bcb = q ? b_c2b   : b_c1b;

        k_cls<<<1, 128, 0, stream>>>(W_m1a, b_m1a, emb, clsA, clsB);
        k_nodesV<<<(MTOT*128)/256, 256, 0, stream>>>(state, action, Wi, bi, q, V);
        k_knn<<<(MTOT+127)/128, 128, 0, stream>>>(state, action, q, idx);
        dim3 gAB(MTOT/64, 4);
        k_AB<<<gAB, 256, 0, stream>>>(V, Wcomb, clsA, clsB, A, B);
        k_edge_mfma<<<MTOT/16, 256, 0, stream>>>(A, B, idx, Wb16, b_m1b, V);  // E aliases V
        k_head<<<MTOT/8, 128, 0, stream>>>(V, Wca, bca, Wcb, bcb, out, q*MTOT);
    }
}

// Round 7
// 324.442 us; speedup vs baseline: 1.7121x; 1.2072x over previous
//
#include <hip/hip_runtime.h>

#define BSZ 512
#define NNODE 30
#define KNBR 15
#define HID 128
#define MTOT (BSZ*NNODE)   // 15360

typedef __attribute__((ext_vector_type(8))) __bf16 bf16x8;
typedef __attribute__((ext_vector_type(4))) float f32x4;

__device__ __forceinline__ float frelu(float x){ return x > 0.f ? x : 0.f; }

// node coordinates per Q layout
__device__ __forceinline__ void node_coords(const float* __restrict__ st,
                                            const float* __restrict__ ac,
                                            int b, int n, int qsel, float c[4]) {
    if (qsel == 0) {
        c[0] = st[b*60 + 2*n];     c[1] = st[b*60 + 2*n + 1];
        c[2] = ac[b*60 + 2*n];     c[3] = ac[b*60 + 2*n + 1];
    } else {
        int base = 4*n;
        if (base < 60) {
            c[0]=st[b*60+base]; c[1]=st[b*60+base+1]; c[2]=st[b*60+base+2]; c[3]=st[b*60+base+3];
        } else {
            int a = base - 60;
            c[0]=ac[b*60+a]; c[1]=ac[b*60+a+1]; c[2]=ac[b*60+a+2]; c[3]=ac[b*60+a+3];
        }
    }
}

// Wcomb16[256][128] bf16: rows 0..127 = Wa_L - Wa_R (v-part), rows 128..255 = Wa_R (v-part)
__global__ void k_wcomb(const float* __restrict__ Wa, __bf16* __restrict__ Wc16) {
    int t = blockIdx.x*256 + threadIdx.x;
    if (t >= 256*128) return;
    int o = t >> 7, h = t & 127;
    float v;
    if (o < 128) v = Wa[o*388 + h] - Wa[o*388 + 194 + h];
    else         v = Wa[(o-128)*388 + 194 + h];
    Wc16[t] = (__bf16)v;
}

// Wb (128x128 fp32, row-major [o][h]) -> bf16
__global__ void k_wb16(const float* __restrict__ W, __bf16* __restrict__ W16) {
    int t = blockIdx.x*256 + threadIdx.x;
    if (t < 128*128) W16[t] = (__bf16)W[t];
}

// clsA[c][o] = (Wa_L-Wa_R)[:,128:192] @ relu(emb[c]) + b_m1a ;  clsB[c][o] = Wa_R[:,128:192] @ relu(emb[c])
__global__ void k_cls(const float* __restrict__ Wa, const float* __restrict__ ba,
                      const float* __restrict__ emb,
                      float* __restrict__ clsA, float* __restrict__ clsB) {
    int o = threadIdx.x;   // 128 threads
    for (int c = 0; c < 3; ++c) {
        float sA = ba[o], sB = 0.f;
        for (int e = 0; e < 64; ++e) {
            float r  = frelu(emb[c*64 + e]);
            float wl = Wa[o*388 + 128 + e];
            float wr = Wa[o*388 + 194 + 128 + e];
            sA += (wl - wr) * r;
            sB += wr * r;
        }
        clsA[c*128 + o] = sA;
        clsB[c*128 + o] = sB;
    }
}

// V[m][h] = relu(W_init @ node_m + b_init), stored bf16 for the MFMA GEMM
__global__ void k_nodesV(const float* __restrict__ st, const float* __restrict__ ac,
                         const float* __restrict__ Wi, const float* __restrict__ bi,
                         int qsel, __bf16* __restrict__ Vb) {
    int gid = blockIdx.x*256 + threadIdx.x;
    if (gid >= MTOT*128) return;
    int m = gid >> 7, h = gid & 127;
    int b = m / 30, n = m % 30;
    float c[4]; node_coords(st, ac, b, n, qsel, c);
    float acc = bi[h] + Wi[h*4+0]*c[0] + Wi[h*4+1]*c[1] + Wi[h*4+2]*c[2] + Wi[h*4+3]*c[3];
    Vb[m*128 + h] = (__bf16)frelu(acc);
}

// exact kNN (matches top_k(-d,k): strictly-smallest-first, ties -> lower index)
__global__ void k_knn(const float* __restrict__ st, const float* __restrict__ ac,
                      int qsel, int* __restrict__ idx) {
    int gid = blockIdx.x*128 + threadIdx.x;
    if (gid >= MTOT) return;
    int b = gid / 30, i = gid % 30;
    float ci[4]; node_coords(st, ac, b, i, qsel, ci);
    float d[30];
    #pragma unroll
    for (int j = 0; j < 30; ++j) {
        float cj[4]; node_coords(st, ac, b, j, qsel, cj);
        float d0 = ci[0]-cj[0], d1 = ci[1]-cj[1], d2 = ci[2]-cj[2], d3 = ci[3]-cj[3];
        d[j] = d0*d0 + d1*d1 + d2*d2 + d3*d3;
    }
    unsigned mask = 1u << i;   // exclude self
    for (int k = 0; k < KNBR; ++k) {
        float best = 3.4e38f; int bj = 0;
        #pragma unroll
        for (int j = 0; j < 30; ++j) {
            bool ok = !((mask >> j) & 1u) && (d[j] < best);
            if (ok) { best = d[j]; bj = j; }
        }
        mask |= 1u << bj;
        idx[gid*KNBR + k] = b*30 + bj;   // store global node index
    }
}

// MFMA [A;B] GEMM: wave = 16-row m-tile x 64-col n-strip. No LDS.
// A-frag: Vb rows (m0+l15), B-frag: Wc16 rows (n0+nc*16+l15). fp32 cls bias epilogue.
__global__ void __launch_bounds__(256) k_AB_mfma(
        const __bf16* __restrict__ Vb, const __bf16* __restrict__ Wc16,
        const float* __restrict__ clsA, const float* __restrict__ clsB,
        float* __restrict__ A, float* __restrict__ B) {
    int tid = threadIdx.x;
    int lane = tid & 63, wid = tid >> 6;
    int l15 = lane & 15, g = lane >> 4;
    int m0 = (blockIdx.x*4 + wid) * 16;
    int n0 = blockIdx.y * 64;    // strips 0,1 -> A ; 2,3 -> B

    bf16x8 wf[4][4];
    #pragma unroll
    for (int nc = 0; nc < 4; ++nc)
        #pragma unroll
        for (int kk = 0; kk < 4; ++kk)
            wf[nc][kk] = *(const bf16x8*)(Wc16 + (n0 + nc*16 + l15)*128 + kk*32 + g*8);

    bf16x8 af[4];
    #pragma unroll
    for (int kk = 0; kk < 4; ++kk)
        af[kk] = *(const bf16x8*)(Vb + (m0 + l15)*128 + kk*32 + g*8);

    f32x4 acc[4];
    #pragma unroll
    for (int nc = 0; nc < 4; ++nc) acc[nc] = (f32x4){0.f,0.f,0.f,0.f};
    #pragma unroll
    for (int kk = 0; kk < 4; ++kk)
        #pragma unroll
        for (int nc = 0; nc < 4; ++nc)
            acc[nc] = __builtin_amdgcn_mfma_f32_16x16x32_bf16(af[kk], wf[nc][kk], acc[nc], 0, 0, 0);

    bool isA = (n0 < 128);
    const float* cls = isA ? clsA : clsB;
    float* dst = isA ? A : B;
    int ob = n0 & 127;
    // D layout: col = l15 (n within 16-tile), row = g*4 + r (m within 16-tile)
    #pragma unroll
    for (int r = 0; r < 4; ++r) {
        int m = m0 + g*4 + r;
        int cat = (m % 30) / 10;
        #pragma unroll
        for (int nc = 0; nc < 4; ++nc) {
            int o = ob + nc*16 + l15;
            dst[m*128 + o] = acc[nc][r] + cls[cat*128 + o];
        }
    }
}

// MFMA edge kernel: E[m][o] = relu( max_j (Wb @ relu(A_m + B_j))[o] + bb[o] )
__global__ void __launch_bounds__(256) k_edge_mfma(
        const float* __restrict__ A, const float* __restrict__ B,
        const int* __restrict__ idx, const __bf16* __restrict__ Wb16,
        const float* __restrict__ bb, float* __restrict__ E) {
    int tid = threadIdx.x;
    int lane = tid & 63, wid = tid >> 6;
    int l15 = lane & 15, g = lane >> 4;

    bf16x8 wbf[8][4];
    #pragma unroll
    for (int oc = 0; oc < 8; ++oc)
        #pragma unroll
        for (int kk = 0; kk < 4; ++kk)
            wbf[oc][kk] = *(const bf16x8*)(Wb16 + (oc*16 + l15)*128 + kk*32 + g*8);

    float bbv[8];
    #pragma unroll
    for (int oc = 0; oc < 8; ++oc) bbv[oc] = bb[oc*16 + l15];

    int jc = (l15 == 15) ? 0 : l15;   // edge row for this lane (15 -> dup of 0)

    for (int n = 0; n < 4; ++n) {
        int m = blockIdx.x*16 + wid*4 + n;
        int nb = idx[m*15 + jc];

        bf16x8 hf[4];
        #pragma unroll
        for (int kk = 0; kk < 4; ++kk) {
            const float4* pa = (const float4*)(A + m*128 + kk*32 + g*8);
            const float4* pb = (const float4*)(B + (long)nb*128 + kk*32 + g*8);
            float4 a0 = pa[0], a1 = pa[1];
            float4 b0 = pb[0], b1 = pb[1];
            bf16x8 h;
            h[0]=(__bf16)frelu(a0.x+b0.x); h[1]=(__bf16)frelu(a0.y+b0.y);
            h[2]=(__bf16)frelu(a0.z+b0.z); h[3]=(__bf16)frelu(a0.w+b0.w);
            h[4]=(__bf16)frelu(a1.x+b1.x); h[5]=(__bf16)frelu(a1.y+b1.y);
            h[6]=(__bf16)frelu(a1.z+b1.z); h[7]=(__bf16)frelu(a1.w+b1.w);
            hf[kk] = h;
        }

        f32x4 acc[8];
        #pragma unroll
        for (int oc = 0; oc < 8; ++oc) acc[oc] = (f32x4){0.f,0.f,0.f,0.f};
        #pragma unroll
        for (int kk = 0; kk < 4; ++kk)
            #pragma unroll
            for (int oc = 0; oc < 8; ++oc)
                acc[oc] = __builtin_amdgcn_mfma_f32_16x16x32_bf16(hf[kk], wbf[oc][kk], acc[oc], 0, 0, 0);

        #pragma unroll
        for (int oc = 0; oc < 8; ++oc) {
            float v = fmaxf(fmaxf(acc[oc][0], acc[oc][1]), fmaxf(acc[oc][2], acc[oc][3]));
            v = fmaxf(v, __shfl_xor(v, 16));
            v = fmaxf(v, __shfl_xor(v, 32));
            if (g == 0) E[m*128 + oc*16 + l15] = frelu(v + bbv[oc]);
        }
    }
}

// q[m] = Wcb @ relu(Wca @ E_m + bca) + bcb. 8 nodes/block, 128 threads.
// Single-barrier parallel reduction (16 lanes per node).
__global__ void __launch_bounds__(128) k_head(const float* __restrict__ E, const float* __restrict__ Wca,
                                              const float* __restrict__ bca, const float* __restrict__ Wcb,
                                              const float* __restrict__ bcb,
                                              float* __restrict__ out, int qoff) {
    __shared__ float Es[8][128];
    __shared__ float red[8][132];
    int t = threadIdx.x;
    int m0 = blockIdx.x * 8;
    for (int f = t; f < 8*32; f += 128) {
        int nd = f >> 5, h4 = f & 31;
        *(float4*)&Es[nd][h4*4] = *(const float4*)&E[(m0+nd)*128 + h4*4];
    }
    __syncthreads();
    float acc[8] = {};
    const float4* W4 = (const float4*)Wca;
    for (int h4 = 0; h4 < 32; ++h4) {
        float4 w = W4[t*32 + h4];
        #pragma unroll
        for (int nd = 0; nd < 8; ++nd) {
            float4 e = *(float4*)&Es[nd][h4*4];
            acc[nd] += w.x*e.x + w.y*e.y + w.z*e.z + w.w*e.w;
        }
    }
    float wcb = Wcb[t], bca_t = bca[t], bcbv = bcb[0];
    #pragma unroll
    for (int nd = 0; nd < 8; ++nd) red[nd][t] = frelu(acc[nd] + bca_t) * wcb;
    __syncthreads();
    int nd = t >> 4, s = t & 15;
    float sum = 0.f;
    #pragma unroll
    for (int i = 0; i < 8; ++i) sum += red[nd][s + i*16];
    sum += __shfl_xor(sum, 8);
    sum += __shfl_xor(sum, 4);
    sum += __shfl_xor(sum, 2);
    sum += __shfl_xor(sum, 1);
    if (s == 0) out[qoff + m0 + nd] = sum + bcbv;
}

extern "C" void kernel_launch(void* const* d_in, const int* in_sizes, int n_in,
                              void* d_out, int out_size, void* d_ws, size_t ws_size,
                              hipStream_t stream) {
    const float* state  = (const float*)d_in[0];
    const float* action = (const float*)d_in[1];
    const float* W_init1= (const float*)d_in[2];
    const float* b_init1= (const float*)d_in[3];
    const float* emb1   = (const float*)d_in[4];
    const float* W_m1a  = (const float*)d_in[5];
    const float* b_m1a  = (const float*)d_in[6];
    const float* W_m1b  = (const float*)d_in[7];
    const float* b_m1b  = (const float*)d_in[8];
    const float* W_c1a  = (const float*)d_in[9];
    const float* b_c1a  = (const float*)d_in[10];
    const float* W_c1b  = (const float*)d_in[11];
    const float* b_c1b  = (const float*)d_in[12];
    const float* W_init2= (const float*)d_in[13];
    const float* b_init2= (const float*)d_in[14];
    const float* emb2   = (const float*)d_in[15];
    const float* W_c2a  = (const float*)d_in[16];
    const float* b_c2a  = (const float*)d_in[17];
    const float* W_c2b  = (const float*)d_in[18];
    const float* b_c2b  = (const float*)d_in[19];

    float* ws    = (float*)d_ws;
    // layout (floats from ws):
    float* E     = ws;                          // 1,966,080 fp32 (E) — first half doubles as Vb (bf16)
    __bf16* Vb   = (__bf16*)ws;                 // bf16 V, dead before E is written
    float* A     = ws + 1966080;
    float* B     = A + 1966080;
    int*   idx   = (int*)(B + 1966080);         // 230,400 ints
    __bf16* Wc16 = (__bf16*)(B + 1966080 + 230400);      // 32768 bf16
    __bf16* Wb16 = Wc16 + 32768;                         // 16384 bf16
    float* clsA  = (float*)(Wb16 + 16384);               // 384
    float* clsB  = clsA + 384;                           // 384
    float* out   = (float*)d_out;

    k_wcomb<<<128, 256, 0, stream>>>(W_m1a, Wc16);
    k_wb16<<<64, 256, 0, stream>>>(W_m1b, Wb16);

    for (int q = 0; q < 2; ++q) {
        const float* Wi  = q ? W_init2 : W_init1;
        const float* bi  = q ? b_init2 : b_init1;
        const float* emb = q ? emb2    : emb1;
        const float* Wca = q ? W_c2a   : W_c1a;
        const float* bca = q ? b_c2a   : b_c1a;
        const float* Wcb = q ? W_c2b   : W_c1b;
        const float* bcb = q ? b_c2b   : b_c1b;

        k_cls<<<1, 128, 0, stream>>>(W_m1a, b_m1a, emb, clsA, clsB);
        k_nodesV<<<(MTOT*128)/256, 256, 0, stream>>>(state, action, Wi, bi, q, Vb);
        k_knn<<<(MTOT+127)/128, 128, 0, stream>>>(state, action, q, idx);
        dim3 gAB(MTOT/64, 4);   // 240 x 4 blocks
        k_AB_mfma<<<gAB, 256, 0, stream>>>(Vb, Wc16, clsA, clsB, A, B);
        k_edge_mfma<<<MTOT/16, 256, 0, stream>>>(A, B, idx, Wb16, b_m1b, E);
        k_head<<<MTOT/8, 128, 0, stream>>>(E, Wca, bca, Wcb, bcb, out, q*MTOT);
    }
}

// Round 8
// 197.737 us; speedup vs baseline: 2.8091x; 1.6408x over previous
//
#include <hip/hip_runtime.h>

#define BSZ 512
#define NNODE 30
#define KNBR 15
#define HID 128
#define MTOT (BSZ*NNODE)   // 15360

typedef __attribute__((ext_vector_type(8))) __bf16 bf16x8;
typedef __attribute__((ext_vector_type(4))) float f32x4;

__device__ __forceinline__ float frelu(float x){ return x > 0.f ? x : 0.f; }

// node coordinates per Q layout
__device__ __forceinline__ void node_coords(const float* __restrict__ st,
                                            const float* __restrict__ ac,
                                            int b, int n, int qsel, float c[4]) {
    if (qsel == 0) {
        c[0] = st[b*60 + 2*n];     c[1] = st[b*60 + 2*n + 1];
        c[2] = ac[b*60 + 2*n];     c[3] = ac[b*60 + 2*n + 1];
    } else {
        int base = 4*n;
        if (base < 60) {
            c[0]=st[b*60+base]; c[1]=st[b*60+base+1]; c[2]=st[b*60+base+2]; c[3]=st[b*60+base+3];
        } else {
            int a = base - 60;
            c[0]=ac[b*60+a]; c[1]=ac[b*60+a+1]; c[2]=ac[b*60+a+2]; c[3]=ac[b*60+a+3];
        }
    }
}

// One prep kernel: all weight bf16 conversions + cls bias folds for both Qs.
// blocks 0..319: elementwise converts (81920 elems). block 320/321: cls q0/q1.
__global__ void k_prep(const float* __restrict__ Wa,  const float* __restrict__ Wb,
                       const float* __restrict__ Wca1,const float* __restrict__ Wca2,
                       const float* __restrict__ ba,
                       const float* __restrict__ emb1,const float* __restrict__ emb2,
                       __bf16* __restrict__ Wc16, __bf16* __restrict__ Wb16,
                       __bf16* __restrict__ Wca16_1, __bf16* __restrict__ Wca16_2,
                       float* __restrict__ cls1A, float* __restrict__ cls1B,
                       float* __restrict__ cls2A, float* __restrict__ cls2B) {
    int blk = blockIdx.x;
    if (blk < 320) {
        int t = blk*256 + threadIdx.x;
        if (t < 32768) {            // Wcomb: [0..127]=Wa_L-Wa_R, [128..255]=Wa_R (v-part)
            int o = t >> 7, h = t & 127;
            float v = (o < 128) ? (Wa[o*388 + h] - Wa[o*388 + 194 + h])
                                : Wa[(o-128)*388 + 194 + h];
            Wc16[t] = (__bf16)v;
        } else if (t < 49152) { int u = t - 32768; Wb16[u]    = (__bf16)Wb[u]; }
        else if (t < 65536)   { int u = t - 49152; Wca16_1[u] = (__bf16)Wca1[u]; }
        else                  { int u = t - 65536; Wca16_2[u] = (__bf16)Wca2[u]; }
    } else {
        int o = threadIdx.x;
        if (o >= 128) return;
        const float* emb = (blk == 320) ? emb1  : emb2;
        float* cA        = (blk == 320) ? cls1A : cls2A;
        float* cB        = (blk == 320) ? cls1B : cls2B;
        for (int c = 0; c < 3; ++c) {
            float sA = ba[o], sB = 0.f;
            for (int e = 0; e < 64; ++e) {
                float r  = frelu(emb[c*64 + e]);
                float wl = Wa[o*388 + 128 + e];
                float wr = Wa[o*388 + 194 + 128 + e];
                sA += (wl - wr) * r;
                sB += wr * r;
            }
            cA[c*128 + o] = sA;
            cB[c*128 + o] = sB;
        }
    }
}

// Fully fused per-Q critic: block = one sample (30 nodes), 256 threads (4 waves).
// coords -> kNN -> V -> [A;B] MFMA -> edge MFMA -> head MFMA, all in LDS.
__global__ void __launch_bounds__(256) k_fused(
        const float* __restrict__ st, const float* __restrict__ ac, int qsel,
        const float* __restrict__ Wi, const float* __restrict__ bi,
        const __bf16* __restrict__ Wc16,
        const float* __restrict__ clsA, const float* __restrict__ clsB,
        const __bf16* __restrict__ Wb16, const float* __restrict__ bb,
        const __bf16* __restrict__ Wca16, const float* __restrict__ bca,
        const float* __restrict__ Wcb, const float* __restrict__ bcb,
        float* __restrict__ out, int qoff) {
    __shared__ float  coords[30][4];
    __shared__ int    idxs[30*16];
    __shared__ __bf16 Vf[2][4][4][16][8];   // [mtile][kk][g][row][8] fragment layout
    __shared__ float  Al[30*132];           // row stride 132 -> 4-bank rotation
    __shared__ float  Bl[30*132];
    __shared__ __bf16 El[32*136];           // bf16 E, rows 30/31 zero pad
    __shared__ float  redh[4][16];

    int tid  = threadIdx.x;
    int lane = tid & 63, wid = tid >> 6;
    int l15  = lane & 15, g = (lane >> 4) & 3;
    int b    = blockIdx.x;

    // phase 0: coords
    if (tid < 30) {
        float c[4]; node_coords(st, ac, b, tid, qsel, c);
        coords[tid][0]=c[0]; coords[tid][1]=c[1]; coords[tid][2]=c[2]; coords[tid][3]=c[3];
    }
    __syncthreads();

    // phase 1: kNN on wave0 lanes 0..29; V on threads 32..255
    if (tid < 30) {
        int i = tid;
        float ci0=coords[i][0], ci1=coords[i][1], ci2=coords[i][2], ci3=coords[i][3];
        float d[30];
        #pragma unroll
        for (int j = 0; j < 30; ++j) {
            float d0 = ci0-coords[j][0], d1 = ci1-coords[j][1];
            float d2 = ci2-coords[j][2], d3 = ci3-coords[j][3];
            d[j] = d0*d0 + d1*d1 + d2*d2 + d3*d3;
        }
        unsigned mask = 1u << i;
        for (int k = 0; k < KNBR; ++k) {
            float best = 3.4e38f; int bj = 0;
            #pragma unroll
            for (int j = 0; j < 30; ++j) {
                bool ok = !((mask >> j) & 1u) && (d[j] < best);
                if (ok) { best = d[j]; bj = j; }
            }
            mask |= 1u << bj;
            idxs[i*16 + k] = bj;           // local node index
        }
        idxs[i*16 + 15] = idxs[i*16];      // dup edge 0 into row 15
    } else if (tid >= 32) {
        for (int e = tid - 32; e < 4096; e += 224) {
            int m = e >> 7, h = e & 127;
            float v = 0.f;
            if (m < 30) {
                v = frelu(bi[h] + Wi[h*4+0]*coords[m][0] + Wi[h*4+1]*coords[m][1]
                                + Wi[h*4+2]*coords[m][2] + Wi[h*4+3]*coords[m][3]);
            }
            Vf[m>>4][h>>5][(h>>3)&3][m&15][h&7] = (__bf16)v;
        }
    }
    __syncthreads();

    // phase 2: [A;B] = V @ Wcomb^T + cls bias. wave: mt = wid&1, half = wid>>1 (0:A 1:B)
    {
        int mt = wid & 1, half = wid >> 1;
        bf16x8 af[4];
        #pragma unroll
        for (int kk = 0; kk < 4; ++kk) af[kk] = *(const bf16x8*)&Vf[mt][kk][g][l15][0];
        f32x4 acc[8];
        #pragma unroll
        for (int nc = 0; nc < 8; ++nc) acc[nc] = (f32x4){0.f,0.f,0.f,0.f};
        #pragma unroll
        for (int nc = 0; nc < 8; ++nc) {
            int o256 = half*128 + nc*16 + l15;
            bf16x8 wf[4];
            #pragma unroll
            for (int kk = 0; kk < 4; ++kk)
                wf[kk] = *(const bf16x8*)(Wc16 + o256*128 + kk*32 + g*8);
            #pragma unroll
            for (int kk = 0; kk < 4; ++kk)
                acc[nc] = __builtin_amdgcn_mfma_f32_16x16x32_bf16(af[kk], wf[kk], acc[nc], 0, 0, 0);
        }
        const float* cls = half ? clsB : clsA;
        float* dst = half ? Bl : Al;
        #pragma unroll
        for (int nc = 0; nc < 8; ++nc) {
            #pragma unroll
            for (int r = 0; r < 4; ++r) {
                int m = mt*16 + g*4 + r;
                if (m < 30) {
                    int o = nc*16 + l15;
                    int cat = m / 10;
                    dst[m*132 + o] = acc[nc][r] + cls[cat*128 + o];
                }
            }
        }
    }
    __syncthreads();

    // phase 3: edge MFMA. E[i][o] = relu(max_j (Wb @ relu(A_i + B_j))[o] + bb[o])
    {
        bf16x8 wbf[8][4];
        #pragma unroll
        for (int oc = 0; oc < 8; ++oc)
            #pragma unroll
            for (int kk = 0; kk < 4; ++kk)
                wbf[oc][kk] = *(const bf16x8*)(Wb16 + (oc*16 + l15)*128 + kk*32 + g*8);
        float bbv[8];
        #pragma unroll
        for (int oc = 0; oc < 8; ++oc) bbv[oc] = bb[oc*16 + l15];

        for (int i = wid; i < 30; i += 4) {
            int nb = idxs[i*16 + l15];
            bf16x8 hf[4];
            #pragma unroll
            for (int kk = 0; kk < 4; ++kk) {
                const float4* pa = (const float4*)&Al[i*132  + kk*32 + g*8];
                const float4* pb = (const float4*)&Bl[nb*132 + kk*32 + g*8];
                float4 a0 = pa[0], a1 = pa[1];
                float4 b0 = pb[0], b1 = pb[1];
                bf16x8 h;
                h[0]=(__bf16)frelu(a0.x+b0.x); h[1]=(__bf16)frelu(a0.y+b0.y);
                h[2]=(__bf16)frelu(a0.z+b0.z); h[3]=(__bf16)frelu(a0.w+b0.w);
                h[4]=(__bf16)frelu(a1.x+b1.x); h[5]=(__bf16)frelu(a1.y+b1.y);
                h[6]=(__bf16)frelu(a1.z+b1.z); h[7]=(__bf16)frelu(a1.w+b1.w);
                hf[kk] = h;
            }
            f32x4 acc[8];
            #pragma unroll
            for (int oc = 0; oc < 8; ++oc) acc[oc] = (f32x4){0.f,0.f,0.f,0.f};
            #pragma unroll
            for (int kk = 0; kk < 4; ++kk)
                #pragma unroll
                for (int oc = 0; oc < 8; ++oc)
                    acc[oc] = __builtin_amdgcn_mfma_f32_16x16x32_bf16(hf[kk], wbf[oc][kk], acc[oc], 0, 0, 0);
            #pragma unroll
            for (int oc = 0; oc < 8; ++oc) {
                float v = fmaxf(fmaxf(acc[oc][0], acc[oc][1]), fmaxf(acc[oc][2], acc[oc][3]));
                v = fmaxf(v, __shfl_xor(v, 16));
                v = fmaxf(v, __shfl_xor(v, 32));
                if (g == 0) El[i*136 + oc*16 + l15] = (__bf16)frelu(v + bbv[oc]);
            }
        }
        if (tid < 136) ((unsigned*)El)[2040 + tid] = 0u;   // zero rows 30,31
    }
    __syncthreads();

    // phase 4: head. G = relu(Wca @ E + bca); q = G . Wcb + bcb
    {
        int mt = wid & 1, half = wid >> 1;
        bf16x8 ef[4];
        #pragma unroll
        for (int kk = 0; kk < 4; ++kk)
            ef[kk] = *(const bf16x8*)&El[(mt*16 + l15)*136 + kk*32 + g*8];
        float s[4] = {0.f, 0.f, 0.f, 0.f};
        #pragma unroll
        for (int nc = 0; nc < 4; ++nc) {
            int o = half*64 + nc*16 + l15;
            bf16x8 wf[4];
            #pragma unroll
            for (int kk = 0; kk < 4; ++kk)
                wf[kk] = *(const bf16x8*)(Wca16 + o*128 + kk*32 + g*8);
            f32x4 a = (f32x4){0.f,0.f,0.f,0.f};
            #pragma unroll
            for (int kk = 0; kk < 4; ++kk)
                a = __builtin_amdgcn_mfma_f32_16x16x32_bf16(ef[kk], wf[kk], a, 0, 0, 0);
            float bcav = bca[o], wcbv = Wcb[o];
            #pragma unroll
            for (int r = 0; r < 4; ++r) s[r] += frelu(a[r] + bcav) * wcbv;
        }
        #pragma unroll
        for (int r = 0; r < 4; ++r) {
            s[r] += __shfl_xor(s[r], 1);
            s[r] += __shfl_xor(s[r], 2);
            s[r] += __shfl_xor(s[r], 4);
            s[r] += __shfl_xor(s[r], 8);
        }
        if (l15 == 0) {
            #pragma unroll
            for (int r = 0; r < 4; ++r) redh[wid][g*4 + r] = s[r];
        }
    }
    __syncthreads();
    if (tid < 30) {
        int mt = tid >> 4, mr = tid & 15;
        out[qoff + b*30 + tid] = redh[mt][mr] + redh[mt+2][mr] + bcb[0];
    }
}

extern "C" void kernel_launch(void* const* d_in, const int* in_sizes, int n_in,
                              void* d_out, int out_size, void* d_ws, size_t ws_size,
                              hipStream_t stream) {
    const float* state  = (const float*)d_in[0];
    const float* action = (const float*)d_in[1];
    const float* W_init1= (const float*)d_in[2];
    const float* b_init1= (const float*)d_in[3];
    const float* emb1   = (const float*)d_in[4];
    const float* W_m1a  = (const float*)d_in[5];
    const float* b_m1a  = (const float*)d_in[6];
    const float* W_m1b  = (const float*)d_in[7];
    const float* b_m1b  = (const float*)d_in[8];
    const float* W_c1a  = (const float*)d_in[9];
    const float* b_c1a  = (const float*)d_in[10];
    const float* W_c1b  = (const float*)d_in[11];
    const float* b_c1b  = (const float*)d_in[12];
    const float* W_init2= (const float*)d_in[13];
    const float* b_init2= (const float*)d_in[14];
    const float* emb2   = (const float*)d_in[15];
    const float* W_c2a  = (const float*)d_in[16];
    const float* b_c2a  = (const float*)d_in[17];
    const float* W_c2b  = (const float*)d_in[18];
    const float* b_c2b  = (const float*)d_in[19];

    __bf16* Wc16    = (__bf16*)d_ws;            // 32768
    __bf16* Wb16    = Wc16 + 32768;             // 16384
    __bf16* Wca16_1 = Wb16 + 16384;             // 16384
    __bf16* Wca16_2 = Wca16_1 + 16384;          // 16384
    float*  cls1A   = (float*)(Wca16_2 + 16384);
    float*  cls1B   = cls1A + 384;
    float*  cls2A   = cls1B + 384;
    float*  cls2B   = cls2A + 384;
    float*  out     = (float*)d_out;

    k_prep<<<322, 256, 0, stream>>>(W_m1a, W_m1b, W_c1a, W_c2a, b_m1a, emb1, emb2,
                                    Wc16, Wb16, Wca16_1, Wca16_2,
                                    cls1A, cls1B, cls2A, cls2B);

    k_fused<<<BSZ, 256, 0, stream>>>(state, action, 0, W_init1, b_init1,
                                     Wc16, cls1A, cls1B, Wb16, b_m1b,
                                     Wca16_1, b_c1a, W_c1b, b_c1b, out, 0);
    k_fused<<<BSZ, 256, 0, stream>>>(state, action, 1, W_init2, b_init2,
                                     Wc16, cls2A, cls2B, Wb16, b_m1b,
                                     Wca16_2, b_c2a, W_c2b, b_c2b, out, MTOT);
}

// Round 9
// 173.702 us; speedup vs baseline: 3.1978x; 1.1384x over previous
//
#include <hip/hip_runtime.h>

#define BSZ 512
#define NNODE 30
#define KNBR 15
#define HID 128
#define MTOT (BSZ*NNODE)   // 15360

typedef __attribute__((ext_vector_type(8))) __bf16 bf16x8;
typedef __attribute__((ext_vector_type(4))) float f32x4;

__device__ __forceinline__ float frelu(float x){ return x > 0.f ? x : 0.f; }

__device__ __forceinline__ void node_coords(const float* __restrict__ st,
                                            const float* __restrict__ ac,
                                            int b, int n, int qsel, float c[4]) {
    if (qsel == 0) {
        c[0] = st[b*60 + 2*n];     c[1] = st[b*60 + 2*n + 1];
        c[2] = ac[b*60 + 2*n];     c[3] = ac[b*60 + 2*n + 1];
    } else {
        int base = 4*n;
        if (base < 60) {
            c[0]=st[b*60+base]; c[1]=st[b*60+base+1]; c[2]=st[b*60+base+2]; c[3]=st[b*60+base+3];
        } else {
            int a = base - 60;
            c[0]=ac[b*60+a]; c[1]=ac[b*60+a+1]; c[2]=ac[b*60+a+2]; c[3]=ac[b*60+a+3];
        }
    }
}

// prep: weight bf16 conversions + cls bias folds for both Qs.
__global__ void k_prep(const float* __restrict__ Wa,  const float* __restrict__ Wb,
                       const float* __restrict__ Wca1,const float* __restrict__ Wca2,
                       const float* __restrict__ ba,
                       const float* __restrict__ emb1,const float* __restrict__ emb2,
                       __bf16* __restrict__ Wc16, __bf16* __restrict__ Wb16,
                       __bf16* __restrict__ Wca16_1, __bf16* __restrict__ Wca16_2,
                       float* __restrict__ cls1A, float* __restrict__ cls1B,
                       float* __restrict__ cls2A, float* __restrict__ cls2B) {
    int blk = blockIdx.x;
    if (blk < 320) {
        int t = blk*256 + threadIdx.x;
        if (t < 32768) {
            int o = t >> 7, h = t & 127;
            float v = (o < 128) ? (Wa[o*388 + h] - Wa[o*388 + 194 + h])
                                : Wa[(o-128)*388 + 194 + h];
            Wc16[t] = (__bf16)v;
        } else if (t < 49152) { int u = t - 32768; Wb16[u]    = (__bf16)Wb[u]; }
        else if (t < 65536)   { int u = t - 49152; Wca16_1[u] = (__bf16)Wca1[u]; }
        else                  { int u = t - 65536; Wca16_2[u] = (__bf16)Wca2[u]; }
    } else {
        int o = threadIdx.x;
        if (o >= 128) return;
        const float* emb = (blk == 320) ? emb1  : emb2;
        float* cA        = (blk == 320) ? cls1A : cls2A;
        float* cB        = (blk == 320) ? cls1B : cls2B;
        for (int c = 0; c < 3; ++c) {
            float sA = ba[o], sB = 0.f;
            for (int e = 0; e < 64; ++e) {
                float r  = frelu(emb[c*64 + e]);
                float wl = Wa[o*388 + 128 + e];
                float wr = Wa[o*388 + 194 + 128 + e];
                sA += (wl - wr) * r;
                sB += wr * r;
            }
            cA[c*128 + o] = sA;
            cB[c*128 + o] = sB;
        }
    }
}

// Fully fused critic, both Qs in one grid: block = one (sample, q). 256 thr / 4 waves.
__global__ void __launch_bounds__(256, 4) k_fused(
        const float* __restrict__ st, const float* __restrict__ ac,
        const float* __restrict__ Wi1, const float* __restrict__ bi1,
        const float* __restrict__ Wi2, const float* __restrict__ bi2,
        const __bf16* __restrict__ Wc16,
        const float* __restrict__ cls1A, const float* __restrict__ cls1B,
        const float* __restrict__ cls2A, const float* __restrict__ cls2B,
        const __bf16* __restrict__ Wb16, const float* __restrict__ bb,
        const __bf16* __restrict__ Wca16_1, const float* __restrict__ bca1,
        const float* __restrict__ Wcb1, const float* __restrict__ bcb1,
        const __bf16* __restrict__ Wca16_2, const float* __restrict__ bca2,
        const float* __restrict__ Wcb2, const float* __restrict__ bcb2,
        float* __restrict__ out) {
    __shared__ float  coords[30][4];
    __shared__ int    idxs[30*16];
    __shared__ __align__(16) __bf16 Vf[2][4][4][16][8];   // A-frag layout for phase 2
    __shared__ __align__(16) __bf16 Al[30*136];           // stride 136 (272B, 16B-mult, 4-bank rot)
    __shared__ __align__(16) __bf16 Bl[30*136];
    __shared__ __align__(16) __bf16 El[32*136];           // rows 30/31 zero pad
    __shared__ float  redh[4][16];

    int tid  = threadIdx.x;
    int lane = tid & 63, wid = tid >> 6;
    int l15  = lane & 15, g = (lane >> 4) & 3;
    int bid  = blockIdx.x;
    int q    = bid >> 9, b = bid & 511;

    const float* Wi   = q ? Wi2 : Wi1;
    const float* bi   = q ? bi2 : bi1;
    const float* clsA = q ? cls2A : cls1A;
    const float* clsB = q ? cls2B : cls1B;
    const __bf16* Wca16 = q ? Wca16_2 : Wca16_1;
    const float* bca  = q ? bca2 : bca1;
    const float* Wcb  = q ? Wcb2 : Wcb1;
    const float* bcb  = q ? bcb2 : bcb1;

    // phase 0: coords
    if (tid < 30) {
        float c[4]; node_coords(st, ac, b, tid, q, c);
        coords[tid][0]=c[0]; coords[tid][1]=c[1]; coords[tid][2]=c[2]; coords[tid][3]=c[3];
    }
    __syncthreads();

    // phase 1: kNN on wave0 lanes 0..29; V on threads 32..255
    if (tid < 30) {
        int i = tid;
        float ci0=coords[i][0], ci1=coords[i][1], ci2=coords[i][2], ci3=coords[i][3];
        float d[30];
        #pragma unroll
        for (int j = 0; j < 30; ++j) {
            float d0 = ci0-coords[j][0], d1 = ci1-coords[j][1];
            float d2 = ci2-coords[j][2], d3 = ci3-coords[j][3];
            d[j] = d0*d0 + d1*d1 + d2*d2 + d3*d3;
        }
        unsigned mask = 1u << i;
        for (int k = 0; k < KNBR; ++k) {
            float best = 3.4e38f; int bj = 0;
            #pragma unroll
            for (int j = 0; j < 30; ++j) {
                bool ok = !((mask >> j) & 1u) && (d[j] < best);
                if (ok) { best = d[j]; bj = j; }
            }
            mask |= 1u << bj;
            idxs[i*16 + k] = bj;
        }
        idxs[i*16 + 15] = idxs[i*16];      // dup edge 0 into row 15
    } else if (tid >= 32) {
        for (int e = tid - 32; e < 4096; e += 224) {
            int m = e >> 7, h = e & 127;
            float v = 0.f;
            if (m < 30) {
                v = frelu(bi[h] + Wi[h*4+0]*coords[m][0] + Wi[h*4+1]*coords[m][1]
                                + Wi[h*4+2]*coords[m][2] + Wi[h*4+3]*coords[m][3]);
            }
            Vf[m>>4][h>>5][(h>>3)&3][m&15][h&7] = (__bf16)v;
        }
    }
    if (tid >= 30 && tid < 32) { }         // idle
    __syncthreads();

    // phase 2: [A;B] = V @ Wcomb^T + cls bias -> bf16 LDS. wave: mt = wid&1, half = wid>>1
    {
        int mt = wid & 1, half = wid >> 1;
        bf16x8 af[4];
        #pragma unroll
        for (int kk = 0; kk < 4; ++kk) af[kk] = *(const bf16x8*)&Vf[mt][kk][g][l15][0];
        f32x4 acc[8];
        #pragma unroll
        for (int nc = 0; nc < 8; ++nc) acc[nc] = (f32x4){0.f,0.f,0.f,0.f};
        #pragma unroll
        for (int nc = 0; nc < 8; ++nc) {
            int o256 = half*128 + nc*16 + l15;
            bf16x8 wf[4];
            #pragma unroll
            for (int kk = 0; kk < 4; ++kk)
                wf[kk] = *(const bf16x8*)(Wc16 + o256*128 + kk*32 + g*8);
            #pragma unroll
            for (int kk = 0; kk < 4; ++kk)
                acc[nc] = __builtin_amdgcn_mfma_f32_16x16x32_bf16(af[kk], wf[kk], acc[nc], 0, 0, 0);
        }
        const float* cls = half ? clsB : clsA;
        __bf16* dst = half ? Bl : Al;
        #pragma unroll
        for (int nc = 0; nc < 8; ++nc) {
            #pragma unroll
            for (int r = 0; r < 4; ++r) {
                int m = mt*16 + g*4 + r;
                if (m < 30) {
                    int o = nc*16 + l15;
                    int cat = m / 10;
                    dst[m*136 + o] = (__bf16)(acc[nc][r] + cls[cat*128 + o]);
                }
            }
        }
    }
    __syncthreads();

    // phase 3: edge MFMA, oc-chunked (2 x 4 oc) to keep weight frags at 64 VGPRs.
    {
        for (int ch = 0; ch < 2; ++ch) {
            bf16x8 wbf[4][4];
            #pragma unroll
            for (int oc = 0; oc < 4; ++oc)
                #pragma unroll
                for (int kk = 0; kk < 4; ++kk)
                    wbf[oc][kk] = *(const bf16x8*)(Wb16 + ((ch*4+oc)*16 + l15)*128 + kk*32 + g*8);
            float bbv[4];
            #pragma unroll
            for (int oc = 0; oc < 4; ++oc) bbv[oc] = bb[(ch*4+oc)*16 + l15];

            for (int i = wid; i < 30; i += 4) {
                int nb = idxs[i*16 + l15];
                bf16x8 hf[4];
                #pragma unroll
                for (int kk = 0; kk < 4; ++kk) {
                    bf16x8 pa = *(const bf16x8*)&Al[i*136  + kk*32 + g*8];
                    bf16x8 pb = *(const bf16x8*)&Bl[nb*136 + kk*32 + g*8];
                    bf16x8 h;
                    #pragma unroll
                    for (int e = 0; e < 8; ++e)
                        h[e] = (__bf16)frelu((float)pa[e] + (float)pb[e]);
                    hf[kk] = h;
                }
                f32x4 acc[4];
                #pragma unroll
                for (int oc = 0; oc < 4; ++oc) acc[oc] = (f32x4){0.f,0.f,0.f,0.f};
                #pragma unroll
                for (int kk = 0; kk < 4; ++kk)
                    #pragma unroll
                    for (int oc = 0; oc < 4; ++oc)
                        acc[oc] = __builtin_amdgcn_mfma_f32_16x16x32_bf16(hf[kk], wbf[oc][kk], acc[oc], 0, 0, 0);
                #pragma unroll
                for (int oc = 0; oc < 4; ++oc) {
                    float v = fmaxf(fmaxf(acc[oc][0], acc[oc][1]), fmaxf(acc[oc][2], acc[oc][3]));
                    v = fmaxf(v, __shfl_xor(v, 16));
                    v = fmaxf(v, __shfl_xor(v, 32));
                    if (g == 0) El[i*136 + (ch*4+oc)*16 + l15] = (__bf16)frelu(v + bbv[oc]);
                }
            }
        }
        if (tid < 136) ((unsigned*)El)[2040 + tid] = 0u;   // zero rows 30,31
    }
    __syncthreads();

    // phase 4: head. G = relu(Wca @ E + bca); q_m = G . Wcb + bcb
    {
        int mt = wid & 1, half = wid >> 1;
        bf16x8 ef[4];
        #pragma unroll
        for (int kk = 0; kk < 4; ++kk)
            ef[kk] = *(const bf16x8*)&El[(mt*16 + l15)*136 + kk*32 + g*8];
        float s[4] = {0.f, 0.f, 0.f, 0.f};
        #pragma unroll
        for (int nc = 0; nc < 4; ++nc) {
            int o = half*64 + nc*16 + l15;
            bf16x8 wf[4];
            #pragma unroll
            for (int kk = 0; kk < 4; ++kk)
                wf[kk] = *(const bf16x8*)(Wca16 + o*128 + kk*32 + g*8);
            f32x4 a = (f32x4){0.f,0.f,0.f,0.f};
            #pragma unroll
            for (int kk = 0; kk < 4; ++kk)
                a = __builtin_amdgcn_mfma_f32_16x16x32_bf16(ef[kk], wf[kk], a, 0, 0, 0);
            float bcav = bca[o], wcbv = Wcb[o];
            #pragma unroll
            for (int r = 0; r < 4; ++r) s[r] += frelu(a[r] + bcav) * wcbv;
        }
        #pragma unroll
        for (int r = 0; r < 4; ++r) {
            s[r] += __shfl_xor(s[r], 1);
            s[r] += __shfl_xor(s[r], 2);
            s[r] += __shfl_xor(s[r], 4);
            s[r] += __shfl_xor(s[r], 8);
        }
        if (l15 == 0) {
            #pragma unroll
            for (int r = 0; r < 4; ++r) redh[wid][g*4 + r] = s[r];
        }
    }
    __syncthreads();
    if (tid < 30) {
        int mt = tid >> 4, mr = tid & 15;
        out[q*MTOT + b*30 + tid] = redh[mt][mr] + redh[mt+2][mr] + bcb[0];
    }
}

extern "C" void kernel_launch(void* const* d_in, const int* in_sizes, int n_in,
                              void* d_out, int out_size, void* d_ws, size_t ws_size,
                              hipStream_t stream) {
    const float* state  = (const float*)d_in[0];
    const float* action = (const float*)d_in[1];
    const float* W_init1= (const float*)d_in[2];
    const float* b_init1= (const float*)d_in[3];
    const float* emb1   = (const float*)d_in[4];
    const float* W_m1a  = (const float*)d_in[5];
    const float* b_m1a  = (const float*)d_in[6];
    const float* W_m1b  = (const float*)d_in[7];
    const float* b_m1b  = (const float*)d_in[8];
    const float* W_c1a  = (const float*)d_in[9];
    const float* b_c1a  = (const float*)d_in[10];
    const float* W_c1b  = (const float*)d_in[11];
    const float* b_c1b  = (const float*)d_in[12];
    const float* W_init2= (const float*)d_in[13];
    const float* b_init2= (const float*)d_in[14];
    const float* emb2   = (const float*)d_in[15];
    const float* W_c2a  = (const float*)d_in[16];
    const float* b_c2a  = (const float*)d_in[17];
    const float* W_c2b  = (const float*)d_in[18];
    const float* b_c2b  = (const float*)d_in[19];

    __bf16* Wc16    = (__bf16*)d_ws;            // 32768
    __bf16* Wb16    = Wc16 + 32768;             // 16384
    __bf16* Wca16_1 = Wb16 + 16384;             // 16384
    __bf16* Wca16_2 = Wca16_1 + 16384;          // 16384
    float*  cls1A   = (float*)(Wca16_2 + 16384);
    float*  cls1B   = cls1A + 384;
    float*  cls2A   = cls1B + 384;
    float*  cls2B   = cls2A + 384;
    float*  out     = (float*)d_out;

    k_prep<<<322, 256, 0, stream>>>(W_m1a, W_m1b, W_c1a, W_c2a, b_m1a, emb1, emb2,
                                    Wc16, Wb16, Wca16_1, Wca16_2,
                                    cls1A, cls1B, cls2A, cls2B);

    k_fused<<<2*BSZ, 256, 0, stream>>>(state, action,
                                       W_init1, b_init1, W_init2, b_init2,
                                       Wc16, cls1A, cls1B, cls2A, cls2B,
                                       Wb16, b_m1b,
                                       Wca16_1, b_c1a, W_c1b, b_c1b,
                                       Wca16_2, b_c2a, W_c2b, b_c2b,
                                       out);
}